// Round 13
// baseline (668.820 us; speedup 1.0000x reference)
//
#include <hip/hip_runtime.h>
#include <hip/hip_bf16.h>

// ---------- types ----------
typedef __attribute__((ext_vector_type(8))) short bf16x8;  // 8 bf16 in 4 VGPRs
typedef __attribute__((ext_vector_type(4))) float f32x4;

__device__ __forceinline__ unsigned short f2bf(float f) {
  union { float f; unsigned u; } v; v.f = f;
  unsigned r = v.u + 0x7FFFu + ((v.u >> 16) & 1u);  // RNE
  return (unsigned short)(r >> 16);
}

__device__ __forceinline__ void gl_lds16(const void* g, void* l) {
  __builtin_amdgcn_global_load_lds(
      (__attribute__((address_space(1))) void*)(g),
      (__attribute__((address_space(3))) void*)(l), 16, 0, 0);
}

// ---------- f32 -> bf16 convert (vectorized) ----------
__global__ __launch_bounds__(256) void k_convert(const float* __restrict__ in,
                                                 unsigned short* __restrict__ out,
                                                 int n8) {
  int i = blockIdx.x * 256 + threadIdx.x;
  if (i >= n8) return;
  const float4* ip = (const float4*)in;
  float4 v0 = ip[2 * i], v1 = ip[2 * i + 1];
  ushort4 o0 = make_ushort4(f2bf(v0.x), f2bf(v0.y), f2bf(v0.z), f2bf(v0.w));
  ushort4 o1 = make_ushort4(f2bf(v1.x), f2bf(v1.y), f2bf(v1.z), f2bf(v1.w));
  ((ushort4*)out)[2 * i] = o0;
  ((ushort4*)out)[2 * i + 1] = o1;
}

// ---------- batched transpose: in [R][C] f32 -> out [C][R] (f32 or bf16) ----------
template <typename OutT>
__global__ __launch_bounds__(256) void k_transpose(const float* __restrict__ in,
                                                   OutT* __restrict__ out,
                                                   int R, int C,
                                                   long inStride, long outStride) {
  __shared__ float tile[64][65];
  const float* ib = in + (long)blockIdx.z * inStride;
  OutT* ob = out + (long)blockIdx.z * outStride;
  int tc = blockIdx.x * 64;
  int tr = blockIdx.y * 64;
  int t = threadIdx.x;
  int lr = t >> 4;
  int lc = (t & 15) * 4;
#pragma unroll
  for (int rr = 0; rr < 64; rr += 16) {
    float4 v = *(const float4*)&ib[(long)(tr + rr + lr) * C + tc + lc];
    tile[rr + lr][lc + 0] = v.x;
    tile[rr + lr][lc + 1] = v.y;
    tile[rr + lr][lc + 2] = v.z;
    tile[rr + lr][lc + 3] = v.w;
  }
  __syncthreads();
#pragma unroll
  for (int ii = 0; ii < 64; ii += 16) {
    int i = ii + lr;
    if constexpr (sizeof(OutT) == 2) {
      ushort4 w = make_ushort4(f2bf(tile[lc + 0][i]), f2bf(tile[lc + 1][i]),
                               f2bf(tile[lc + 2][i]), f2bf(tile[lc + 3][i]));
      *(ushort4*)&ob[(long)(tc + i) * R + tr + lc] = w;
    } else {
      float4 w = make_float4(tile[lc + 0][i], tile[lc + 1][i],
                             tile[lc + 2][i], tile[lc + 3][i]);
      *(float4*)&ob[(long)(tc + i) * R + tr + lc] = w;
    }
  }
}

// ---------- fused: B_in f32 -> Xbf_B bf16 (rows offset 32768) AND BinT bf16 ----------
__global__ __launch_bounds__(256) void k_convtrans_B(const float* __restrict__ in,
                                                     unsigned short* __restrict__ xbf,
                                                     unsigned short* __restrict__ bt) {
  __shared__ float tile[64][65];
  const int bz = blockIdx.z;
  const float* ib = in + (long)bz * 786432L;
  unsigned short* ob = bt + (long)bz * 786432L;
  int tc = blockIdx.x * 64;  // D dim (768)
  int tr = blockIdx.y * 64;  // S dim (1024)
  int t = threadIdx.x;
  int lr = t >> 4;
  int lc = (t & 15) * 4;
#pragma unroll
  for (int rr = 0; rr < 64; rr += 16) {
    float4 v = *(const float4*)&ib[(long)(tr + rr + lr) * 768 + tc + lc];
    tile[rr + lr][lc + 0] = v.x;
    tile[rr + lr][lc + 1] = v.y;
    tile[rr + lr][lc + 2] = v.z;
    tile[rr + lr][lc + 3] = v.w;
    ushort4 w = make_ushort4(f2bf(v.x), f2bf(v.y), f2bf(v.z), f2bf(v.w));
    *(ushort4*)&xbf[(long)(32768 + bz * 1024 + tr + rr + lr) * 768 + tc + lc] = w;
  }
  __syncthreads();
#pragma unroll
  for (int ii = 0; ii < 64; ii += 16) {
    int i = ii + lr;
    ushort4 w = make_ushort4(f2bf(tile[lc + 0][i]), f2bf(tile[lc + 1][i]),
                             f2bf(tile[lc + 2][i]), f2bf(tile[lc + 3][i]));
    *(ushort4*)&ob[(long)(tc + i) * 1024 + tr + lc] = w;
  }
}

// ---------- combine per-block partial stats -> rowM/rowIS, colM/colIS ----------
__global__ __launch_bounds__(256) void k_statcombine(
    const float* __restrict__ rowPM, const float* __restrict__ rowPS,
    const float* __restrict__ colPM, const float* __restrict__ colPS,
    float* __restrict__ rowM, float* __restrict__ rowIS,
    float* __restrict__ colM, float* __restrict__ colIS) {
  int idx = blockIdx.x * 256 + threadIdx.x;  // 0..65535
  if (idx < 32768) {
    int z = idx >> 10, i = idx & 1023;
    float mv[4], sv[4];
    float m = -3.4e38f;
#pragma unroll
    for (int k = 0; k < 4; ++k) {
      mv[k] = rowPM[((long)z * 4 + k) * 1024 + i];
      sv[k] = rowPS[((long)z * 4 + k) * 1024 + i];
      m = fmaxf(m, mv[k]);
    }
    float s = 0.f;
#pragma unroll
    for (int k = 0; k < 4; ++k) s += sv[k] * __expf(mv[k] - m);
    rowM[idx] = m;
    rowIS[idx] = 1.0f / s;
  } else {
    int j = idx - 32768;
    int z = j >> 10, c = j & 1023;
    float mv[8], sv[8];
    float m = -3.4e38f;
#pragma unroll
    for (int k = 0; k < 8; ++k) {
      mv[k] = colPM[((long)z * 8 + k) * 1024 + c];
      sv[k] = colPS[((long)z * 8 + k) * 1024 + c];
      m = fmaxf(m, mv[k]);
    }
    float s = 0.f;
#pragma unroll
    for (int k = 0; k < 8; ++k) s += sv[k] * __expf(mv[k] - m);
    colM[j] = m;
    colIS[j] = 1.0f / s;
  }
}

// ---------- GEMM-BT: C[m,n] = sum_k A[m,k] * Bt[n,k] ----------
// Block tile 128M x 256N, BK=64, 256 threads = 4 waves (2x2), wave tile 64x128.
// Round-8 proven structure. Z-SPLIT merges two batched GEMMs into one dispatch.
// STATS: E-GEMM epilogue emits partial row/col softmax stats from accumulators.
// SMODE==1 (P@B): A-operand is softmax(E) computed on the fly — reg-stage E f32,
// exp+scale in-register (beta: row stats; alpha: col stats), pack bf16,
// swizzled ds_write. Removes the 262MB softmax-apply pass entirely.
// sA/sB = rowM/rowIS (beta) , sC/sD = colM/colIS (alpha) when SMODE==1;
// same slots are rowPM/rowPS/colPM/colPS partial-outputs when STATS.
template <bool BIAS_RELU, bool OUT_BF16, bool STATS, int SMODE>
__global__ __launch_bounds__(256, 2) void k_gemm_bt(
    const unsigned short* __restrict__ A, long lda, long aBatch,
    const unsigned short* __restrict__ A2,
    const unsigned short* __restrict__ Bt, long ldb, long bBatch,
    void* __restrict__ C, void* __restrict__ C2, long ldc, long cBatch,
    const float* __restrict__ bias, int K, int zsplit,
    float* __restrict__ sA, float* __restrict__ sB,
    float* __restrict__ sC, float* __restrict__ sD) {
  __shared__ unsigned short As[128 * 64];  // M x BK
  __shared__ unsigned short Bs[256 * 64];  // N x BK
  const int t = threadIdx.x;
  const int w = t >> 6, l = t & 63;
  const int lr = l & 15, lh = l >> 4;
  const int wm = w >> 1, wn = w & 1;  // wave tile 64M x 128N

  // XCD-affinity remap (grid size % 8 == 0 guaranteed by launcher)
  const int gx = gridDim.x, gy = gridDim.y;
  const int nwg = gx * gy * gridDim.z;
  const int hw = blockIdx.x + gx * (blockIdx.y + gy * blockIdx.z);
  const int q = nwg >> 3;
  const int logical = (hw & 7) * q + (hw >> 3);
  const int bx = logical % gx;
  const int rem = logical / gx;
  const int by = rem % gy;
  int bz = rem / gy;

  const unsigned short* Abase = A;
  void* Cbase = C;
  bool alphaP = false;
  if (bz >= zsplit) { Abase = A2; Cbase = C2; bz -= zsplit; alphaP = true; }

  const long m0 = (long)by * 128;
  const long n0 = (long)bx * 256;
  const unsigned short* Ab = Abase + (long)bz * aBatch;
  const unsigned short* Bb = Bt + (long)bz * bBatch;

  // staging geometry (both modes): thread t covers rows srow+{0,32,64,96},
  // 16B chunk index c = t&7. LDS[row][x] = A[row][x ^ (row&7)] (both paths).
  const int srow = t >> 3;                       // 0..31
  const int c8 = t & 7;
  const int sc16 = c8 ^ (srow & 7);              // swizzled chunk
  const int scol = sc16 * 8;                     // in shorts
  const unsigned short* ag = Ab + (m0 + srow) * lda + scol;
  const unsigned short* bg = Bb + (n0 + srow) * ldb + scol;
  unsigned short* al = &As[srow * 64 + c8 * 8];
  unsigned short* bl = &Bs[srow * 64 + c8 * 8];

  // SMODE1: E panel (f32) + row-stat hoists
  const float* Epan = nullptr;
  float rmv[4], riv[4];
  if constexpr (SMODE == 1) {
    Epan = (const float*)Abase + (long)bz * 1048576L;
    if (!alphaP) {
#pragma unroll
      for (int j = 0; j < 4; ++j) {
        long r = (long)bz * 1024 + m0 + srow + j * 32;
        rmv[j] = sA[r];
        riv[j] = sB[r];
      }
    }
  }

  f32x4 acc[4][8];
#pragma unroll
  for (int i = 0; i < 4; ++i)
#pragma unroll
    for (int j = 0; j < 8; ++j) acc[i][j] = (f32x4){0.f, 0.f, 0.f, 0.f};

  for (int k0 = 0; k0 < K; k0 += 64) {
#pragma unroll
    for (int j = 0; j < 8; ++j)
      gl_lds16(bg + (long)(j * 32) * ldb + k0, bl + j * 2048);
    if constexpr (SMODE == 0) {
#pragma unroll
      for (int j = 0; j < 4; ++j)
        gl_lds16(ag + (long)(j * 32) * lda + k0, al + j * 2048);
    } else {
      // softmax-fused A staging: E f32 -> exp/scale -> bf16 -> swizzled ds_write
      float sub[8], mul[8];
      if (alphaP) {
        long cbase = (long)bz * 1024 + k0 + c8 * 8;
        float4 cm0 = *(const float4*)&sC[cbase];
        float4 cm1 = *(const float4*)&sC[cbase + 4];
        float4 ci0 = *(const float4*)&sD[cbase];
        float4 ci1 = *(const float4*)&sD[cbase + 4];
        sub[0] = cm0.x; sub[1] = cm0.y; sub[2] = cm0.z; sub[3] = cm0.w;
        sub[4] = cm1.x; sub[5] = cm1.y; sub[6] = cm1.z; sub[7] = cm1.w;
        mul[0] = ci0.x; mul[1] = ci0.y; mul[2] = ci0.z; mul[3] = ci0.w;
        mul[4] = ci1.x; mul[5] = ci1.y; mul[6] = ci1.z; mul[7] = ci1.w;
      }
#pragma unroll
      for (int j = 0; j < 4; ++j) {
        const int row = srow + j * 32;
        const float* src = Epan + (long)(m0 + row) * 1024 + k0 + c8 * 8;
        float4 e0 = *(const float4*)src;
        float4 e1 = *(const float4*)(src + 4);
        float ev[8] = {e0.x, e0.y, e0.z, e0.w, e1.x, e1.y, e1.z, e1.w};
        union { unsigned short us[8]; int4 qd; } pk;
        if (alphaP) {
#pragma unroll
          for (int e = 0; e < 8; ++e)
            pk.us[e] = f2bf(__expf(ev[e] - sub[e]) * mul[e]);
        } else {
          float rm = rmv[j], ri = riv[j];
#pragma unroll
          for (int e = 0; e < 8; ++e)
            pk.us[e] = f2bf(__expf(ev[e] - rm) * ri);
        }
        *(int4*)&As[row * 64 + sc16 * 8] = pk.qd;
      }
    }
    __syncthreads();
#pragma unroll
    for (int kk = 0; kk < 2; ++kk) {
      const int rsw = ((kk * 4 + lh) ^ (lr & 7)) * 8;  // read-side swizzled chunk
      bf16x8 af[4], bfr[8];
#pragma unroll
      for (int m = 0; m < 4; ++m)
        af[m] = *(const bf16x8*)&As[(wm * 64 + m * 16 + lr) * 64 + rsw];
#pragma unroll
      for (int n = 0; n < 8; ++n)
        bfr[n] = *(const bf16x8*)&Bs[(wn * 128 + n * 16 + lr) * 64 + rsw];
#pragma unroll
      for (int m = 0; m < 4; ++m)
#pragma unroll
        for (int n = 0; n < 8; ++n)
          acc[m][n] = __builtin_amdgcn_mfma_f32_16x16x32_bf16(af[m], bfr[n], acc[m][n], 0, 0, 0);
    }
    __syncthreads();
  }

  const long crow = m0 + wm * 64;
  const long ccol = n0 + wn * 128;
#pragma unroll
  for (int n = 0; n < 8; ++n) {
    const long col = ccol + n * 16 + lr;
    float bv = 0.f;
    if constexpr (BIAS_RELU) bv = bias[col];
#pragma unroll
    for (int m = 0; m < 4; ++m) {
      f32x4 v = acc[m][n];
#pragma unroll
      for (int r = 0; r < 4; ++r) {
        const long rrow = crow + m * 16 + lh * 4 + r;
        float x = v[r];
        if constexpr (BIAS_RELU) x = fmaxf(x + bv, 0.f);
        if constexpr (OUT_BF16)
          ((unsigned short*)Cbase)[(long)bz * cBatch + rrow * ldc + col] = f2bf(x);
        else
          ((float*)Cbase)[(long)bz * cBatch + rrow * ldc + col] = x;
      }
    }
  }

  if constexpr (STATS) {
    float* ldsRM = (float*)As;          // [128][2] row max per wn
    float* ldsRS = (float*)As + 256;    // [128][2] row sumexp per wn
    float* ldsCM = (float*)Bs;          // [256][2] col max per wm
    float* ldsCS = (float*)Bs + 512;    // [256][2] col sumexp per wm
#pragma unroll
    for (int m = 0; m < 4; ++m) {
#pragma unroll
      for (int r = 0; r < 4; ++r) {
        float lm = acc[m][0][r];
#pragma unroll
        for (int n = 1; n < 8; ++n) lm = fmaxf(lm, acc[m][n][r]);
#pragma unroll
        for (int o = 1; o < 16; o <<= 1) lm = fmaxf(lm, __shfl_xor(lm, o));
        float ls = 0.f;
#pragma unroll
        for (int n = 0; n < 8; ++n) ls += __expf(acc[m][n][r] - lm);
#pragma unroll
        for (int o = 1; o < 16; o <<= 1) ls += __shfl_xor(ls, o);
        if (lr == 0) {
          int row = wm * 64 + m * 16 + lh * 4 + r;
          ldsRM[row * 2 + wn] = lm;
          ldsRS[row * 2 + wn] = ls;
        }
      }
    }
#pragma unroll
    for (int n = 0; n < 8; ++n) {
      float lm = acc[0][n][0];
#pragma unroll
      for (int m = 0; m < 4; ++m)
#pragma unroll
        for (int r = 0; r < 4; ++r) lm = fmaxf(lm, acc[m][n][r]);
#pragma unroll
      for (int o = 16; o < 64; o <<= 1) lm = fmaxf(lm, __shfl_xor(lm, o));
      float ls = 0.f;
#pragma unroll
      for (int m = 0; m < 4; ++m)
#pragma unroll
        for (int r = 0; r < 4; ++r) ls += __expf(acc[m][n][r] - lm);
#pragma unroll
      for (int o = 16; o < 64; o <<= 1) ls += __shfl_xor(ls, o);
      if (lh == 0) {
        int col = wn * 128 + n * 16 + lr;
        ldsCM[col * 2 + wm] = lm;
        ldsCS[col * 2 + wm] = ls;
      }
    }
    __syncthreads();
    if (t < 128) {
      float m0v = ldsRM[t * 2], m1v = ldsRM[t * 2 + 1];
      float s0v = ldsRS[t * 2], s1v = ldsRS[t * 2 + 1];
      float mm = fmaxf(m0v, m1v);
      float ss = s0v * __expf(m0v - mm) + s1v * __expf(m1v - mm);
      long o = ((long)bz * 4 + bx) * 1024 + by * 128 + t;
      sA[o] = mm;
      sB[o] = ss;
    }
    {
      float m0v = ldsCM[t * 2], m1v = ldsCM[t * 2 + 1];
      float s0v = ldsCS[t * 2], s1v = ldsCS[t * 2 + 1];
      float mm = fmaxf(m0v, m1v);
      float ss = s0v * __expf(m0v - mm) + s1v * __expf(m1v - mm);
      long o = ((long)bz * 8 + by) * 1024 + bx * 256 + t;
      sC[o] = mm;
      sD[o] = ss;
    }
  }
}

// ---------- launcher ----------
extern "C" void kernel_launch(void* const* d_in, const int* in_sizes, int n_in,
                              void* d_out, int out_size, void* d_ws, size_t ws_size,
                              hipStream_t stream) {
  const float* A_in = (const float*)d_in[0];  // [32,1024,768]
  const float* B_in = (const float*)d_in[1];  // [32,1024,768]
  const float* W1 = (const float*)d_in[2];    // [768,1024]
  const float* b1 = (const float*)d_in[3];    // [1024]
  const float* W2 = (const float*)d_in[4];    // [1024,1024]
  const float* b2 = (const float*)d_in[5];    // [1024]

  char* ws = (char*)d_ws;
  // Region timeline (sequential dispatches make each clobber safe):
  //   [0,100MB)   Xbf (X rows A then B)     — dead after MLP1; then E [0,128MiB)
  //   [100,235MB) H                          — dead after MLP2; E tail overlaps
  //   [140MiB..]  stats (written by E-GEMM, after MLP2)
  //   [235,369MB) F                          — dead after E-GEMM
  //   [369,417MB) BinT ; [417..423MB) W1T/W2T
  unsigned short* Xbf  = (unsigned short*)(ws + 0L);
  unsigned short* H    = (unsigned short*)(ws + 100663296L);
  unsigned short* F    = (unsigned short*)(ws + 234881024L);
  unsigned short* BinT = (unsigned short*)(ws + 369098752L);
  unsigned short* W1T  = (unsigned short*)(ws + 419430400L);
  unsigned short* W2T  = (unsigned short*)(ws + 421003264L);
  float* E = (float*)(ws + 0L);                       // 32x1024x1024 f32 = 128MiB
  float* rowPM = (float*)(ws + 146800640L);           // [32][4][1024]
  float* rowPS = (float*)(ws + 146800640L + 524288L);
  float* colPM = (float*)(ws + 146800640L + 1048576L);  // [32][8][1024]
  float* colPS = (float*)(ws + 146800640L + 2097152L);
  float* rowM  = (float*)(ws + 146800640L + 3145728L);  // [32][1024]
  float* rowIS = (float*)(ws + 146800640L + 3276800L);
  float* colM  = (float*)(ws + 146800640L + 3407872L);
  float* colIS = (float*)(ws + 146800640L + 3538944L);
  float* beta = (float*)d_out;
  float* alpha = (float*)d_out + 25165824L;
  const int NOSPLIT = 1 << 30;

  // 1) input conditioning
  k_convert<<<12288, 256, 0, stream>>>(A_in, Xbf, 3145728);
  k_convtrans_B<<<dim3(12, 16, 32), 256, 0, stream>>>(B_in, Xbf, BinT);
  k_transpose<unsigned short><<<dim3(16, 12, 1), 256, 0, stream>>>(W1, W1T, 768, 1024, 0, 0);
  k_transpose<unsigned short><<<dim3(16, 16, 1), 256, 0, stream>>>(W2, W2T, 1024, 1024, 0, 0);

  // 2) MLP: H = relu(X@W1+b1); F = relu(H@W2+b2)
  k_gemm_bt<true, true, false, 0><<<dim3(4, 512, 1), 256, 0, stream>>>(
      Xbf, 768, 0, nullptr, W1T, 768, 0, (void*)H, nullptr, 1024, 0, b1, 768, NOSPLIT,
      nullptr, nullptr, nullptr, nullptr);
  k_gemm_bt<true, true, false, 0><<<dim3(4, 512, 1), 256, 0, stream>>>(
      H, 1024, 0, nullptr, W2T, 1024, 0, (void*)F, nullptr, 1024, 0, b2, 1024, NOSPLIT,
      nullptr, nullptr, nullptr, nullptr);

  // 3) E[b] = fA[b] @ fB[b]^T (f32 -> ws), fused partial softmax stats
  k_gemm_bt<false, false, true, 0><<<dim3(4, 8, 32), 256, 0, stream>>>(
      F, 1024, 1048576L, nullptr, F + 33554432L, 1024, 1048576L, (void*)E, nullptr,
      1024, 1048576L, nullptr, 1024, NOSPLIT, rowPM, rowPS, colPM, colPS);

  // 4) combine partial stats (softmax-apply is fused into step 5)
  k_statcombine<<<256, 256, 0, stream>>>(rowPM, rowPS, colPM, colPS,
                                         rowM, rowIS, colM, colIS);

  // 5) beta = rowsoftmax(E) @ B ; alpha = colsoftmax(E) @ B — one merged
  //    dispatch; A-operand staged from E f32 with on-the-fly exp/scale.
  k_gemm_bt<false, false, false, 1><<<dim3(3, 8, 64), 256, 0, stream>>>(
      (const unsigned short*)E, 1024, 1048576L, (const unsigned short*)E,
      BinT, 1024, 786432L, (void*)beta, (void*)alpha,
      768, 786432L, nullptr, 1024, 32, rowM, rowIS, colM, colIS);
}

// Round 14
// 642.884 us; speedup vs baseline: 1.0403x; 1.0403x over previous
//
#include <hip/hip_runtime.h>
#include <hip/hip_bf16.h>

// ---------- types ----------
typedef __attribute__((ext_vector_type(8))) short bf16x8;  // 8 bf16 in 4 VGPRs
typedef __attribute__((ext_vector_type(4))) float f32x4;

__device__ __forceinline__ unsigned short f2bf(float f) {
  union { float f; unsigned u; } v; v.f = f;
  unsigned r = v.u + 0x7FFFu + ((v.u >> 16) & 1u);  // RNE
  return (unsigned short)(r >> 16);
}

__device__ __forceinline__ void gl_lds16(const void* g, void* l) {
  __builtin_amdgcn_global_load_lds(
      (__attribute__((address_space(1))) void*)(g),
      (__attribute__((address_space(3))) void*)(l), 16, 0, 0);
}

// ---------- f32 -> bf16 convert (vectorized) ----------
__global__ __launch_bounds__(256) void k_convert(const float* __restrict__ in,
                                                 unsigned short* __restrict__ out,
                                                 int n8) {
  int i = blockIdx.x * 256 + threadIdx.x;
  if (i >= n8) return;
  const float4* ip = (const float4*)in;
  float4 v0 = ip[2 * i], v1 = ip[2 * i + 1];
  ushort4 o0 = make_ushort4(f2bf(v0.x), f2bf(v0.y), f2bf(v0.z), f2bf(v0.w));
  ushort4 o1 = make_ushort4(f2bf(v1.x), f2bf(v1.y), f2bf(v1.z), f2bf(v1.w));
  ((ushort4*)out)[2 * i] = o0;
  ((ushort4*)out)[2 * i + 1] = o1;
}

// ---------- batched transpose: in [R][C] f32 -> out [C][R] (f32 or bf16) ----------
template <typename OutT>
__global__ __launch_bounds__(256) void k_transpose(const float* __restrict__ in,
                                                   OutT* __restrict__ out,
                                                   int R, int C,
                                                   long inStride, long outStride) {
  __shared__ float tile[64][65];
  const float* ib = in + (long)blockIdx.z * inStride;
  OutT* ob = out + (long)blockIdx.z * outStride;
  int tc = blockIdx.x * 64;
  int tr = blockIdx.y * 64;
  int t = threadIdx.x;
  int lr = t >> 4;
  int lc = (t & 15) * 4;
#pragma unroll
  for (int rr = 0; rr < 64; rr += 16) {
    float4 v = *(const float4*)&ib[(long)(tr + rr + lr) * C + tc + lc];
    tile[rr + lr][lc + 0] = v.x;
    tile[rr + lr][lc + 1] = v.y;
    tile[rr + lr][lc + 2] = v.z;
    tile[rr + lr][lc + 3] = v.w;
  }
  __syncthreads();
#pragma unroll
  for (int ii = 0; ii < 64; ii += 16) {
    int i = ii + lr;
    if constexpr (sizeof(OutT) == 2) {
      ushort4 w = make_ushort4(f2bf(tile[lc + 0][i]), f2bf(tile[lc + 1][i]),
                               f2bf(tile[lc + 2][i]), f2bf(tile[lc + 3][i]));
      *(ushort4*)&ob[(long)(tc + i) * R + tr + lc] = w;
    } else {
      float4 w = make_float4(tile[lc + 0][i], tile[lc + 1][i],
                             tile[lc + 2][i], tile[lc + 3][i]);
      *(float4*)&ob[(long)(tc + i) * R + tr + lc] = w;
    }
  }
}

// ---------- fused: B_in f32 -> Xbf_B bf16 (rows offset 32768) AND BinT bf16 ----------
__global__ __launch_bounds__(256) void k_convtrans_B(const float* __restrict__ in,
                                                     unsigned short* __restrict__ xbf,
                                                     unsigned short* __restrict__ bt) {
  __shared__ float tile[64][65];
  const int bz = blockIdx.z;
  const float* ib = in + (long)bz * 786432L;
  unsigned short* ob = bt + (long)bz * 786432L;
  int tc = blockIdx.x * 64;  // D dim (768)
  int tr = blockIdx.y * 64;  // S dim (1024)
  int t = threadIdx.x;
  int lr = t >> 4;
  int lc = (t & 15) * 4;
#pragma unroll
  for (int rr = 0; rr < 64; rr += 16) {
    float4 v = *(const float4*)&ib[(long)(tr + rr + lr) * 768 + tc + lc];
    tile[rr + lr][lc + 0] = v.x;
    tile[rr + lr][lc + 1] = v.y;
    tile[rr + lr][lc + 2] = v.z;
    tile[rr + lr][lc + 3] = v.w;
    ushort4 w = make_ushort4(f2bf(v.x), f2bf(v.y), f2bf(v.z), f2bf(v.w));
    *(ushort4*)&xbf[(long)(32768 + bz * 1024 + tr + rr + lr) * 768 + tc + lc] = w;
  }
  __syncthreads();
#pragma unroll
  for (int ii = 0; ii < 64; ii += 16) {
    int i = ii + lr;
    ushort4 w = make_ushort4(f2bf(tile[lc + 0][i]), f2bf(tile[lc + 1][i]),
                             f2bf(tile[lc + 2][i]), f2bf(tile[lc + 3][i]));
    *(ushort4*)&ob[(long)(tc + i) * 1024 + tr + lc] = w;
  }
}

// ---------- combine per-block partial stats -> rowM/rowIS, colM/colIS ----------
// rows: [32][4 xblk][1024] partials ; cols: [32][8 yblk][1024] partials.
__global__ __launch_bounds__(256) void k_statcombine(
    const float* __restrict__ rowPM, const float* __restrict__ rowPS,
    const float* __restrict__ colPM, const float* __restrict__ colPS,
    float* __restrict__ rowM, float* __restrict__ rowIS,
    float* __restrict__ colM, float* __restrict__ colIS) {
  int idx = blockIdx.x * 256 + threadIdx.x;  // 0..65535
  if (idx < 32768) {
    int z = idx >> 10, i = idx & 1023;
    float mv[4], sv[4];
    float m = -3.4e38f;
#pragma unroll
    for (int k = 0; k < 4; ++k) {
      mv[k] = rowPM[((long)z * 4 + k) * 1024 + i];
      sv[k] = rowPS[((long)z * 4 + k) * 1024 + i];
      m = fmaxf(m, mv[k]);
    }
    float s = 0.f;
#pragma unroll
    for (int k = 0; k < 4; ++k) s += sv[k] * __expf(mv[k] - m);
    rowM[idx] = m;
    rowIS[idx] = 1.0f / s;
  } else {
    int j = idx - 32768;
    int z = j >> 10, c = j & 1023;
    float mv[8], sv[8];
    float m = -3.4e38f;
#pragma unroll
    for (int k = 0; k < 8; ++k) {
      mv[k] = colPM[((long)z * 8 + k) * 1024 + c];
      sv[k] = colPS[((long)z * 8 + k) * 1024 + c];
      m = fmaxf(m, mv[k]);
    }
    float s = 0.f;
#pragma unroll
    for (int k = 0; k < 8; ++k) s += sv[k] * __expf(mv[k] - m);
    colM[j] = m;
    colIS[j] = 1.0f / s;
  }
}

// ---------- pure-streaming softmax apply: E -> P (row-softmax), P2 (col-softmax) ----------
__global__ __launch_bounds__(256) void k_softmax(const float* __restrict__ E,
                                                 unsigned short* __restrict__ P,
                                                 unsigned short* __restrict__ P2,
                                                 const float* __restrict__ rowM,
                                                 const float* __restrict__ rowIS,
                                                 const float* __restrict__ colM,
                                                 const float* __restrict__ colIS) {
  long row = blockIdx.x;
  int t = threadIdx.x;
  float4 v = *(const float4*)&E[row * 1024 + t * 4];
  float rm = rowM[row], ri = rowIS[row];
  *(ushort4*)&P[row * 1024 + t * 4] =
      make_ushort4(f2bf(__expf(v.x - rm) * ri), f2bf(__expf(v.y - rm) * ri),
                   f2bf(__expf(v.z - rm) * ri), f2bf(__expf(v.w - rm) * ri));
  long cb = (row >> 10) * 1024 + t * 4;
  float4 cm = *(const float4*)&colM[cb];
  float4 ci = *(const float4*)&colIS[cb];
  *(ushort4*)&P2[row * 1024 + t * 4] =
      make_ushort4(f2bf(__expf(v.x - cm.x) * ci.x), f2bf(__expf(v.y - cm.y) * ci.y),
                   f2bf(__expf(v.z - cm.z) * ci.z), f2bf(__expf(v.w - cm.w) * ci.w));
}

// ---------- GEMM-BT: C[m,n] = sum_k A[m,k] * Bt[n,k]  (both bf16, K-contiguous) ----------
// Block tile 128M x 256N, BK=64, 256 threads = 4 waves (2x2), wave tile 64x128.
// Round-8 proven structure (38-40% MfmaUtil ~ 900 TF, this 2-barrier loop's ceiling).
// Z-SPLIT merges two batched GEMMs into one dispatch. STATS: epilogue computes
// per-block partial row (max,sumexp over 256 cols) and col (over 128 rows) softmax
// stats from the f32 accumulators — removes a whole 134MB stats pass over E.
template <bool BIAS_RELU, bool OUT_BF16, bool STATS>
__global__ __launch_bounds__(256, 2) void k_gemm_bt(
    const unsigned short* __restrict__ A, long lda, long aBatch,
    const unsigned short* __restrict__ A2,
    const unsigned short* __restrict__ Bt, long ldb, long bBatch,
    void* __restrict__ C, void* __restrict__ C2, long ldc, long cBatch,
    const float* __restrict__ bias, int K, int zsplit,
    float* __restrict__ rowPM, float* __restrict__ rowPS,
    float* __restrict__ colPM, float* __restrict__ colPS) {
  __shared__ unsigned short As[128 * 64];  // M x BK
  __shared__ unsigned short Bs[256 * 64];  // N x BK
  const int t = threadIdx.x;
  const int w = t >> 6, l = t & 63;
  const int lr = l & 15, lh = l >> 4;
  const int wm = w >> 1, wn = w & 1;  // wave tile 64M x 128N

  // XCD-affinity remap (grid size % 8 == 0 guaranteed by launcher)
  const int gx = gridDim.x, gy = gridDim.y;
  const int nwg = gx * gy * gridDim.z;
  const int hw = blockIdx.x + gx * (blockIdx.y + gy * blockIdx.z);
  const int q = nwg >> 3;
  const int logical = (hw & 7) * q + (hw >> 3);
  const int bx = logical % gx;
  const int rem = logical / gx;
  const int by = rem % gy;
  int bz = rem / gy;

  const unsigned short* Abase = A;
  void* Cbase = C;
  if (bz >= zsplit) { Abase = A2; Cbase = C2; bz -= zsplit; }

  const long m0 = (long)by * 128;
  const long n0 = (long)bx * 256;
  const unsigned short* Ab = Abase + (long)bz * aBatch;
  const unsigned short* Bb = Bt + (long)bz * bBatch;

  // staging: A = 128 rows (4 rounds), B = 256 rows (8 rounds); 256 threads,
  // each round covers 32 rows x 64 cols. dest = wave-uniform + lane*16 (ok).
  // source chunk pre-swizzled: LDS[row][c] = global[row][c ^ (row&7)].
  const int srow = t >> 3;                       // 0..31
  const int sc16 = (t & 7) ^ (srow & 7);         // swizzled 16B-chunk
  const int scol = sc16 * 8;                     // in shorts
  const unsigned short* ag = Ab + (m0 + srow) * lda + scol;
  const unsigned short* bg = Bb + (n0 + srow) * ldb + scol;
  unsigned short* al = &As[srow * 64 + (t & 7) * 8];
  unsigned short* bl = &Bs[srow * 64 + (t & 7) * 8];

  f32x4 acc[4][8];
#pragma unroll
  for (int i = 0; i < 4; ++i)
#pragma unroll
    for (int j = 0; j < 8; ++j) acc[i][j] = (f32x4){0.f, 0.f, 0.f, 0.f};

  for (int k0 = 0; k0 < K; k0 += 64) {
#pragma unroll
    for (int j = 0; j < 4; ++j)
      gl_lds16(ag + (long)(j * 32) * lda + k0, al + j * 2048);
#pragma unroll
    for (int j = 0; j < 8; ++j)
      gl_lds16(bg + (long)(j * 32) * ldb + k0, bl + j * 2048);
    __syncthreads();
#pragma unroll
    for (int kk = 0; kk < 2; ++kk) {
      const int rsw = ((kk * 4 + lh) ^ (lr & 7)) * 8;  // read-side swizzled chunk
      bf16x8 af[4], bfr[8];
#pragma unroll
      for (int m = 0; m < 4; ++m)
        af[m] = *(const bf16x8*)&As[(wm * 64 + m * 16 + lr) * 64 + rsw];
#pragma unroll
      for (int n = 0; n < 8; ++n)
        bfr[n] = *(const bf16x8*)&Bs[(wn * 128 + n * 16 + lr) * 64 + rsw];
#pragma unroll
      for (int m = 0; m < 4; ++m)
#pragma unroll
        for (int n = 0; n < 8; ++n)
          acc[m][n] = __builtin_amdgcn_mfma_f32_16x16x32_bf16(af[m], bfr[n], acc[m][n], 0, 0, 0);
    }
    __syncthreads();
  }

  const long crow = m0 + wm * 64;
  const long ccol = n0 + wn * 128;
#pragma unroll
  for (int n = 0; n < 8; ++n) {
    const long col = ccol + n * 16 + lr;
    float bv = 0.f;
    if constexpr (BIAS_RELU) bv = bias[col];
#pragma unroll
    for (int m = 0; m < 4; ++m) {
      f32x4 v = acc[m][n];
#pragma unroll
      for (int r = 0; r < 4; ++r) {
        const long rrow = crow + m * 16 + lh * 4 + r;
        float x = v[r];
        if constexpr (BIAS_RELU) x = fmaxf(x + bv, 0.f);
        if constexpr (OUT_BF16)
          ((unsigned short*)Cbase)[(long)bz * cBatch + rrow * ldc + col] = f2bf(x);
        else
          ((float*)Cbase)[(long)bz * cBatch + rrow * ldc + col] = x;
      }
    }
  }

  if constexpr (STATS) {
    // Partial softmax stats from live accumulators (after last K-loop barrier,
    // LDS is free). acc[m][n][r]: row = wm*64+m*16+lh*4+r, col = wn*128+n*16+lr.
    float* ldsRM = (float*)As;          // [128][2] row max per wn
    float* ldsRS = (float*)As + 256;    // [128][2] row sumexp per wn
    float* ldsCM = (float*)Bs;          // [256][2] col max per wm
    float* ldsCS = (float*)Bs + 512;    // [256][2] col sumexp per wm
    // row partials: reduce over n (8 cols) then lr (x16 lanes -> 128 cols)
#pragma unroll
    for (int m = 0; m < 4; ++m) {
#pragma unroll
      for (int r = 0; r < 4; ++r) {
        float lm = acc[m][0][r];
#pragma unroll
        for (int n = 1; n < 8; ++n) lm = fmaxf(lm, acc[m][n][r]);
#pragma unroll
        for (int o = 1; o < 16; o <<= 1) lm = fmaxf(lm, __shfl_xor(lm, o));
        float ls = 0.f;
#pragma unroll
        for (int n = 0; n < 8; ++n) ls += __expf(acc[m][n][r] - lm);
#pragma unroll
        for (int o = 1; o < 16; o <<= 1) ls += __shfl_xor(ls, o);
        if (lr == 0) {
          int row = wm * 64 + m * 16 + lh * 4 + r;
          ldsRM[row * 2 + wn] = lm;
          ldsRS[row * 2 + wn] = ls;
        }
      }
    }
    // col partials: reduce over (m,r) (16 rows) then lh (x4 lanes -> 64 rows)
#pragma unroll
    for (int n = 0; n < 8; ++n) {
      float lm = acc[0][n][0];
#pragma unroll
      for (int m = 0; m < 4; ++m)
#pragma unroll
        for (int r = 0; r < 4; ++r) lm = fmaxf(lm, acc[m][n][r]);
#pragma unroll
      for (int o = 16; o < 64; o <<= 1) lm = fmaxf(lm, __shfl_xor(lm, o));
      float ls = 0.f;
#pragma unroll
      for (int m = 0; m < 4; ++m)
#pragma unroll
        for (int r = 0; r < 4; ++r) ls += __expf(acc[m][n][r] - lm);
#pragma unroll
      for (int o = 16; o < 64; o <<= 1) ls += __shfl_xor(ls, o);
      if (lh == 0) {
        int col = wn * 128 + n * 16 + lr;
        ldsCM[col * 2 + wm] = lm;
        ldsCS[col * 2 + wm] = ls;
      }
    }
    __syncthreads();
    if (t < 128) {
      float m0v = ldsRM[t * 2], m1v = ldsRM[t * 2 + 1];
      float s0v = ldsRS[t * 2], s1v = ldsRS[t * 2 + 1];
      float mm = fmaxf(m0v, m1v);
      float ss = s0v * __expf(m0v - mm) + s1v * __expf(m1v - mm);
      long o = ((long)bz * 4 + bx) * 1024 + by * 128 + t;
      rowPM[o] = mm;
      rowPS[o] = ss;
    }
    {
      float m0v = ldsCM[t * 2], m1v = ldsCM[t * 2 + 1];
      float s0v = ldsCS[t * 2], s1v = ldsCS[t * 2 + 1];
      float mm = fmaxf(m0v, m1v);
      float ss = s0v * __expf(m0v - mm) + s1v * __expf(m1v - mm);
      long o = ((long)bz * 8 + by) * 1024 + bx * 256 + t;
      colPM[o] = mm;
      colPS[o] = ss;
    }
  }
}

// ---------- launcher ----------
extern "C" void kernel_launch(void* const* d_in, const int* in_sizes, int n_in,
                              void* d_out, int out_size, void* d_ws, size_t ws_size,
                              hipStream_t stream) {
  const float* A_in = (const float*)d_in[0];  // [32,1024,768]
  const float* B_in = (const float*)d_in[1];  // [32,1024,768]
  const float* W1 = (const float*)d_in[2];    // [768,1024]
  const float* b1 = (const float*)d_in[3];    // [1024]
  const float* W2 = (const float*)d_in[4];    // [1024,1024]
  const float* b2 = (const float*)d_in[5];    // [1024]

  char* ws = (char*)d_ws;
  unsigned short* Xbf  = (unsigned short*)(ws + 0L);           // 65536x768 bf16 (96MB); later P
  unsigned short* H    = (unsigned short*)(ws + 100663296L);   // 65536x1024 bf16 (128MB); later stats
  unsigned short* F    = (unsigned short*)(ws + 234881024L);   // 65536x1024 bf16 (128MB); later P2
  unsigned short* BinT = (unsigned short*)(ws + 369098752L);   // 32x768x1024 bf16 (48MB)
  unsigned short* W1T  = (unsigned short*)(ws + 419430400L);   // 1024x768 bf16
  unsigned short* W2T  = (unsigned short*)(ws + 421003264L);   // 1024x1024 bf16
  unsigned short* P    = (unsigned short*)(ws + 0L);           // 32x1024x1024 bf16 (64MB)
  unsigned short* P2   = (unsigned short*)(ws + 234881024L);   // 32x1024x1024 bf16 (64MB)
  // softmax stats live in the (free after MLP2) H region:
  float* rowPM = (float*)(ws + 100663296L);                    // [32][4][1024]
  float* rowPS = (float*)(ws + 100663296L + 524288L);
  float* colPM = (float*)(ws + 100663296L + 1048576L);         // [32][8][1024]
  float* colPS = (float*)(ws + 100663296L + 2097152L);
  float* rowM  = (float*)(ws + 100663296L + 3145728L);         // [32][1024]
  float* rowIS = (float*)(ws + 100663296L + 3276800L);
  float* colM  = (float*)(ws + 100663296L + 3407872L);
  float* colIS = (float*)(ws + 100663296L + 3538944L);
  float* E  = (float*)d_out;                                   // 32x1024x1024 f32 (134MB)
  float* beta = (float*)d_out;
  float* alpha = (float*)d_out + 25165824L;
  const int NOSPLIT = 1 << 30;

  // 1) input conditioning: A convert; B fused convert+transpose; W transposes
  k_convert<<<12288, 256, 0, stream>>>(A_in, Xbf, 3145728);
  k_convtrans_B<<<dim3(12, 16, 32), 256, 0, stream>>>(B_in, Xbf, BinT);
  k_transpose<unsigned short><<<dim3(16, 12, 1), 256, 0, stream>>>(W1, W1T, 768, 1024, 0, 0);
  k_transpose<unsigned short><<<dim3(16, 16, 1), 256, 0, stream>>>(W2, W2T, 1024, 1024, 0, 0);

  // 2) MLP: H = relu(X@W1+b1); F = relu(H@W2+b2)
  k_gemm_bt<true, true, false><<<dim3(4, 512, 1), 256, 0, stream>>>(
      Xbf, 768, 0, nullptr, W1T, 768, 0, (void*)H, nullptr, 1024, 0, b1, 768, NOSPLIT,
      nullptr, nullptr, nullptr, nullptr);
  k_gemm_bt<true, true, false><<<dim3(4, 512, 1), 256, 0, stream>>>(
      H, 1024, 0, nullptr, W2T, 1024, 0, (void*)F, nullptr, 1024, 0, b2, 1024, NOSPLIT,
      nullptr, nullptr, nullptr, nullptr);

  // 3) E[b] = fA[b] @ fB[b]^T, with fused partial softmax stats in the epilogue
  k_gemm_bt<false, false, true><<<dim3(4, 8, 32), 256, 0, stream>>>(
      F, 1024, 1048576L, nullptr, F + 33554432L, 1024, 1048576L, (void*)E, nullptr,
      1024, 1048576L, nullptr, 1024, NOSPLIT, rowPM, rowPS, colPM, colPS);

  // 4) combine partial stats; streaming softmax apply (reads E once)
  k_statcombine<<<256, 256, 0, stream>>>(rowPM, rowPS, colPM, colPS,
                                         rowM, rowIS, colM, colIS);
  k_softmax<<<32768, 256, 0, stream>>>(E, P, P2, rowM, rowIS, colM, colIS);

  // 5) beta = P @ B ; alpha = P2 @ B — ONE merged dispatch (1536 blocks, 6/CU)
  k_gemm_bt<false, false, false><<<dim3(3, 8, 64), 256, 0, stream>>>(
      P, 1024, 1048576L, P2, BinT, 1024, 786432L, (void*)beta, (void*)alpha,
      768, 786432L, nullptr, 1024, 32, nullptr, nullptr, nullptr, nullptr);
}